// Round 7
// baseline (498.639 us; speedup 1.0000x reference)
//
#include <hip/hip_runtime.h>
#include <math.h>

// Problem constants (from reference)
constexpr int T    = 8192;   // B*S = 4*2048
constexpr int D    = 1024;
constexpr int HID  = 128;
constexpr int QD   = 32;     // HEADS*K_DIM
constexpr int HEADS = 2;
constexpr int KDIM  = 16;
constexpr int KNN   = 8;
constexpr int NKEYS = 256;
constexpr int HALF  = 8;

// ---------------------------------------------------------------------------
// Kernel A: fused  h = relu(x@W1^T + b1);  q = h@W2^T + b2
// Block: 256 threads, 32 tokens per block. Grid: T/32 = 256 blocks.
// f32 vector-ALU GEMM (no f32 MFMA on CDNA4; bf16 would perturb top-k).
// ---------------------------------------------------------------------------
__global__ __launch_bounds__(256) void mlp_kernel(
    const float* __restrict__ x, const float* __restrict__ W1,
    const float* __restrict__ b1, const float* __restrict__ W2,
    const float* __restrict__ b2, float* __restrict__ qout)
{
    __shared__ float Xs[32][33];    // [k][token]
    __shared__ float Ws[32][132];   // [k][hidden j]
    __shared__ float hs[32][132];   // [token][hidden j]
    __shared__ float w2s[32][132];  // [o][j]

    const int tid = threadIdx.x;
    const int t0  = blockIdx.x * 32;
    const int tx  = tid & 15;        // hidden group (8 each)
    const int ty  = tid >> 4;        // token group (2 each)

    // Stage W2 (32x128) into LDS
    #pragma unroll
    for (int p = 0; p < 4; ++p) {
        int f = p * 1024 + tid * 4;
        int o = f >> 7, j = f & 127;
        *(float4*)&w2s[o][j] = *(const float4*)&W2[f];
    }

    // b1 for my 8 hidden columns
    float b1v[8];
    #pragma unroll
    for (int j = 0; j < 8; ++j) b1v[j] = b1[tx * 8 + j];

    float acc[2][8];
    #pragma unroll
    for (int i = 0; i < 2; ++i)
        #pragma unroll
        for (int j = 0; j < 8; ++j) acc[i][j] = 0.f;

    const int lrow = tid >> 3;         // 0..31
    const int lcol = (tid & 7) * 4;    // 0..28 step 4

    for (int kt = 0; kt < D; kt += 32) {
        __syncthreads();
        // X tile: 32 tokens x 32 d, transposed into Xs[k][m]
        {
            float4 xv = *(const float4*)&x[(t0 + lrow) * D + kt + lcol];
            Xs[lcol + 0][lrow] = xv.x;
            Xs[lcol + 1][lrow] = xv.y;
            Xs[lcol + 2][lrow] = xv.z;
            Xs[lcol + 3][lrow] = xv.w;
        }
        // W1 tile: 128 j x 32 d, transposed into Ws[k][j]
        #pragma unroll
        for (int p = 0; p < 4; ++p) {
            int j = p * 32 + lrow;
            float4 wv = *(const float4*)&W1[j * D + kt + lcol];
            Ws[lcol + 0][j] = wv.x;
            Ws[lcol + 1][j] = wv.y;
            Ws[lcol + 2][j] = wv.z;
            Ws[lcol + 3][j] = wv.w;
        }
        __syncthreads();
        #pragma unroll 8
        for (int k = 0; k < 32; ++k) {
            float a0 = Xs[k][ty * 2 + 0];
            float a1 = Xs[k][ty * 2 + 1];
            const float4 w0 = *(const float4*)&Ws[k][tx * 8];
            const float4 w1v = *(const float4*)&Ws[k][tx * 8 + 4];
            float bw[8] = {w0.x, w0.y, w0.z, w0.w, w1v.x, w1v.y, w1v.z, w1v.w};
            #pragma unroll
            for (int j = 0; j < 8; ++j) {
                acc[0][j] = fmaf(a0, bw[j], acc[0][j]);
                acc[1][j] = fmaf(a1, bw[j], acc[1][j]);
            }
        }
    }
    __syncthreads();
    // relu + bias, stage h to LDS
    #pragma unroll
    for (int i = 0; i < 2; ++i)
        #pragma unroll
        for (int j = 0; j < 8; ++j)
            hs[ty * 2 + i][tx * 8 + j] = fmaxf(acc[i][j] + b1v[j], 0.f);
    __syncthreads();

    // q = h @ W2^T + b2 : 32 tokens x 32 outputs, 4 per thread
    {
        const int o  = tid & 31;
        const int tb = (tid >> 5) * 4;
        const float b2o = b2[o];
        #pragma unroll
        for (int tt = 0; tt < 4; ++tt) {
            int t = tb + tt;
            float s = 0.f;
            #pragma unroll
            for (int j4 = 0; j4 < 128; j4 += 4) {
                float4 hv = *(const float4*)&hs[t][j4];
                float4 wv = *(const float4*)&w2s[o][j4];
                s += hv.x * wv.x + hv.y * wv.y + hv.z * wv.z + hv.w * wv.w;
            }
            qout[(t0 + t) * QD + o] = s + b2o;
        }
    }
}

// ---------------------------------------------------------------------------
// Kernel B: per token (one wave64): scores -> top8 x2 -> 64 combos -> top8
//           -> softmax -> gather+weighted-sum of values rows.
// Tie-breaks match lax.top_k (lower index wins on equal scores).
// ---------------------------------------------------------------------------
__global__ __launch_bounds__(256) void topk_gather_kernel(
    const float* __restrict__ q, const float* __restrict__ keys,
    const float* __restrict__ values, float* __restrict__ out)
{
    const int lane = threadIdx.x & 63;
    const int t = blockIdx.x * 4 + (threadIdx.x >> 6);

    float4 a0 = {0,0,0,0}, a1 = {0,0,0,0}, a2 = {0,0,0,0}, a3 = {0,0,0,0};

    for (int h = 0; h < HEADS; ++h) {
        float sc1[KNN], sc2[KNN];
        int   i1[KNN], i2[KNN];

        for (int side = 0; side < 2; ++side) {
            // broadcast q sub-vector (8)
            float q8[8];
            const float* qp = q + t * QD + h * KDIM + side * HALF;
            #pragma unroll
            for (int c = 0; c < 8; ++c) q8[c] = qp[c];

            // 256 scores, 4 per lane: n = lane + 64*r
            float s[4];
            const float* kb = keys + (size_t)(h * 2 + side) * NKEYS * HALF;
            #pragma unroll
            for (int r = 0; r < 4; ++r) {
                const float* kp = kb + (lane + 64 * r) * 8;
                float4 k0 = *(const float4*)kp;
                float4 k1 = *(const float4*)(kp + 4);
                s[r] = q8[0]*k0.x + q8[1]*k0.y + q8[2]*k0.z + q8[3]*k0.w
                     + q8[4]*k1.x + q8[5]*k1.y + q8[6]*k1.z + q8[7]*k1.w;
            }

            float* scd = side ? sc2 : sc1;
            int*   idd = side ? i2  : i1;
            // 8x argmax extraction (all-lanes butterfly; tie -> lower n)
            for (int it = 0; it < KNN; ++it) {
                float bs = s[0]; int bi = lane;
                #pragma unroll
                for (int r = 1; r < 4; ++r) {
                    if (s[r] > bs) { bs = s[r]; bi = lane + 64 * r; }
                }
                #pragma unroll
                for (int off = 32; off >= 1; off >>= 1) {
                    float os = __shfl_xor(bs, off);
                    int   oi = __shfl_xor(bi, off);
                    if (os > bs || (os == bs && oi < bi)) { bs = os; bi = oi; }
                }
                scd[it] = bs; idd[it] = bi;
                if ((bi & 63) == lane) s[bi >> 6] = -INFINITY;
            }
        }

        // 64 combos, one per lane: combo = a*8 + b = lane
        float cs = sc1[lane >> 3] + sc2[lane & 7];
        float tops[KNN]; int topc[KNN];
        for (int it = 0; it < KNN; ++it) {
            float bs = cs; int bi = lane;
            #pragma unroll
            for (int off = 32; off >= 1; off >>= 1) {
                float os = __shfl_xor(bs, off);
                int   oi = __shfl_xor(bi, off);
                if (os > bs || (os == bs && oi < bi)) { bs = os; bi = oi; }
            }
            tops[it] = bs; topc[it] = bi;
            if (bi == lane) cs = -INFINITY;
        }

        // softmax over the 8 (tops[0] is the max)
        float w[KNN]; float wsum = 0.f;
        #pragma unroll
        for (int k = 0; k < KNN; ++k) { w[k] = expf(tops[k] - tops[0]); wsum += w[k]; }
        const float inv = 1.f / wsum;

        // gather + weighted sum: 8 rows x 1024 f32, float4 per lane
        #pragma unroll
        for (int k = 0; k < KNN; ++k) {
            const int c = topc[k];
            const int row = i1[c >> 3] * NKEYS + i2[c & 7];
            const float wk = w[k] * inv;
            const float4* vp = (const float4*)values + (size_t)row * 256 + lane;
            float4 v0 = vp[0], v1 = vp[64], v2 = vp[128], v3 = vp[192];
            a0.x = fmaf(wk, v0.x, a0.x); a0.y = fmaf(wk, v0.y, a0.y);
            a0.z = fmaf(wk, v0.z, a0.z); a0.w = fmaf(wk, v0.w, a0.w);
            a1.x = fmaf(wk, v1.x, a1.x); a1.y = fmaf(wk, v1.y, a1.y);
            a1.z = fmaf(wk, v1.z, a1.z); a1.w = fmaf(wk, v1.w, a1.w);
            a2.x = fmaf(wk, v2.x, a2.x); a2.y = fmaf(wk, v2.y, a2.y);
            a2.z = fmaf(wk, v2.z, a2.z); a2.w = fmaf(wk, v2.w, a2.w);
            a3.x = fmaf(wk, v3.x, a3.x); a3.y = fmaf(wk, v3.y, a3.y);
            a3.z = fmaf(wk, v3.z, a3.z); a3.w = fmaf(wk, v3.w, a3.w);
        }
    }

    float4* o4 = (float4*)out + (size_t)t * 256 + lane;
    o4[0] = a0; o4[64] = a1; o4[128] = a2; o4[192] = a3;
}

// ---------------------------------------------------------------------------
extern "C" void kernel_launch(void* const* d_in, const int* in_sizes, int n_in,
                              void* d_out, int out_size, void* d_ws, size_t ws_size,
                              hipStream_t stream)
{
    const float* x      = (const float*)d_in[0];
    const float* W1     = (const float*)d_in[1];
    const float* b1     = (const float*)d_in[2];
    const float* W2     = (const float*)d_in[3];
    const float* b2     = (const float*)d_in[4];
    const float* keys   = (const float*)d_in[5];
    const float* values = (const float*)d_in[6];
    float* out = (float*)d_out;
    float* qws = (float*)d_ws;   // T*QD f32 = 1 MB

    mlp_kernel<<<T / 32, 256, 0, stream>>>(x, W1, b1, W2, b2, qws);
    topk_gather_kernel<<<T / 4, 256, 0, stream>>>(qws, keys, values, out);
}